// Round 17
// baseline (650.818 us; speedup 1.0000x reference)
//
#include <hip/hip_runtime.h>
#include <math.h>
#include <stddef.h>

#define NLAYER 24
#define NEMBD  1024
#define NFFN   4096
#define NB     512            // 2 blocks per CU: TLP covers poll-drain stalls
#define NT     256
#define LN_EPS 1e-5f

#define OUT_SA (NEMBD)
#define OUT_SB (NEMBD + NLAYER*NEMBD)
#define OUT_SC (NEMBD + 2*NLAYER*NEMBD)
#define OUT_SD (NEMBD + 3*NLAYER*NEMBD)

typedef unsigned long long u64;
typedef unsigned u32;

// tagged-word queues (u64: tag<<32 | float bits); data IS the sync signal
#define QX_OFF    0        // 1024
#define QW_OFF    1024     // 1024
#define QSXX_OFF  2048     // 1024
#define QKFB_OFF  3072     // 4096
#define QTOTAL    7168

// ---- LDS float offsets (15390 f = 61.6 KB -> 2 blocks/CU fits) ----
#define LFF   0            // 10 x 1024: kffn rows 0..7, rffn rows at 8,9
#define LACT  10240        // 1024: staged w (S2)
#define LMSK  11264        // 3 x 1024: masks (k/v/r at S1; tmk/tmr at S3)
#define LKF   10240        // 4096: kf overlay on LACT+LMSK (dead at S4)
#define LLN   15360        // 8: LN partials
#define LKVR  15368        // 6: [method*2+idx]
#define LXL   15376        // 2
#define LSXL  15378        // 2
#define LRFL  15380        // 2
#define LPT   15382        // 8: [r*4+wave]
#define SMTOT 15390

struct Params {
  const float *x, *state, *ln1w, *ln1b, *ln2w, *ln2b, *td, *tf, *kktk, *vvtv, *rrtr;
  const float *key, *outputv, *tmk, *tmr, *kffn, *rffn, *vffn;
  float *out;
  u64 *q;
};

__device__ __forceinline__ float wred(float v) {
#pragma unroll
  for (int o = 32; o > 0; o >>= 1) v += __shfl_xor(v, o, 64);
  return v;
}
__device__ __forceinline__ float dot4(float4 a, float4 b) {
  return a.x*b.x + a.y*b.y + a.z*b.z + a.w*b.w;
}
__device__ __forceinline__ float fcomp(float4 v, int j) {   // literal j only
  return j == 0 ? v.x : (j == 1 ? v.y : (j == 2 ? v.z : v.w));
}
__device__ __forceinline__ u64 qload(const u64* a) {
  return __hip_atomic_load(a, __ATOMIC_RELAXED, __HIP_MEMORY_SCOPE_AGENT);
}
__device__ __forceinline__ void qput(u64* a, float v, u32 tag) {
  u64 w = ((u64)tag << 32) | (u64)__float_as_uint(v);
  __hip_atomic_store(a, w, __ATOMIC_RELAXED, __HIP_MEMORY_SCOPE_AGENT);
}
__device__ __forceinline__ u32   qtag(u64 w) { return (u32)(w >> 32); }
__device__ __forceinline__ float qval(u64 w) { return __uint_as_float((u32)w); }

// async global->LDS, 16B/lane: dest = wave-uniform base + lane*16
__device__ __forceinline__ void stage16(const float* g, float* l) {
  __builtin_amdgcn_global_load_lds(
      (const __attribute__((address_space(1))) unsigned int*)g,
      (__attribute__((address_space(3))) unsigned int*)l, 16, 0, 0);
}

// intra-block barrier: LDS ordering only; weight vmem stays in flight
__device__ __forceinline__ void lbar() {
  asm volatile("s_waitcnt lgkmcnt(0)" ::: "memory");
  __builtin_amdgcn_s_barrier();
  asm volatile("" ::: "memory");
}

// per-thread poll of its own 4 consecutive words
#define POLL4(QB, IDX, TG, OUTA)                                              \
  do {                                                                        \
    u64 a0_, a1_, a2_, a3_; long cc_ = 0;                                     \
    for (;;) {                                                                \
      a0_ = qload((QB) + (IDX) + 0); a1_ = qload((QB) + (IDX) + 1);           \
      a2_ = qload((QB) + (IDX) + 2); a3_ = qload((QB) + (IDX) + 3);           \
      if (qtag(a0_) >= (TG) && qtag(a1_) >= (TG) &&                           \
          qtag(a2_) >= (TG) && qtag(a3_) >= (TG)) break;                      \
      __builtin_amdgcn_s_sleep(1);                                            \
      if (++cc_ > (1L << 20)) break;  /* safety: wrong beats hang */          \
    }                                                                         \
    OUTA[0] = qval(a0_); OUTA[1] = qval(a1_);                                 \
    OUTA[2] = qval(a2_); OUTA[3] = qval(a3_);                                 \
  } while (0)

__global__ void __launch_bounds__(NT, 2)
rwkv_persistent(Params p) {
  const int b    = blockIdx.x;
  const int t    = threadIdx.x;
  const int wid  = t >> 6;
  const int lane = t & 63;
  const int i0   = t * 4;

  __shared__ float sm[SMTOT];

  u64* QX   = p.q + QX_OFF;
  u64* QW   = p.q + QW_OFF;
  u64* QSXX = p.q + QSXX_OFF;
  u64* QKFB = p.q + QKFB_OFF;

  float4 wKEY[8];    // waves 0-2: method-wid rows for block's 2 indices
  float4 wOV[4];     // waves 0-1: outputv row b*2+wid
  float4 wVF[8];     // all waves: vffn rows {0,1} x K-quarter wid
  float4 pA[6];      // s1 params
  float4 pC[5];      // s3 params
  float s_tf, s_sb, s_sc, s_td;   // wave-3 lanes<2 wkv scalars

  auto loadKEY = [&](int L) {      // method wid, indices 0..1
    if (wid < 3) {
      const float* W = p.key + ((size_t)L * 3 + wid) * NEMBD * NEMBD
                     + (size_t)(b * 2) * NEMBD + lane * 4;
#pragma unroll
      for (int idx = 0; idx < 2; ++idx)
#pragma unroll
        for (int c = 0; c < 4; ++c)
          wKEY[idx * 4 + c] = *(const float4*)&W[(size_t)idx * NEMBD + c * 256];
    }
  };
  auto loadOV = [&](int L) {
    if (wid < 2) {
      const float* W = p.outputv + ((size_t)L * NEMBD + b * 2 + wid) * NEMBD + lane * 4;
#pragma unroll
      for (int c = 0; c < 4; ++c)
        wOV[c] = *(const float4*)&W[c * 256];
    }
  };
  auto loadVF = [&](int L) {       // 2 rows x K-quarter wid
#pragma unroll
    for (int r = 0; r < 2; ++r) {
      const float* W = p.vffn + ((size_t)L * NEMBD + b * 2 + r) * NFFN
                     + wid * 1024 + lane * 4;
#pragma unroll
      for (int c = 0; c < 4; ++c)
        wVF[r * 4 + c] = *(const float4*)&W[c * 256];
    }
  };
  auto stageFF = [&](int L) {      // kffn rows wid*2,wid*2+1; rffn (wid<2)
#pragma unroll
    for (int e = 0; e < 2; ++e) {
      const int f = wid * 2 + e;
      const float* W = p.kffn + ((size_t)L * NFFN + b * 8 + f) * NEMBD + lane * 4;
      float* dst = &sm[LFF + f * 1024];
#pragma unroll
      for (int c = 0; c < 4; ++c) stage16(W + c * 256, dst + c * 256);
    }
    if (wid < 2) {
      const float* Wr = p.rffn + ((size_t)L * NEMBD + b * 2 + wid) * NEMBD + lane * 4;
      float* dr = &sm[LFF + (8 + wid) * 1024];
#pragma unroll
      for (int c = 0; c < 4; ++c) stage16(Wr + c * 256, dr + c * 256);
    }
  };
  auto loadPA = [&](int L) {
    const int o = L * NEMBD + i0;
    pA[0] = *(const float4*)&p.ln1w[o];
    pA[1] = *(const float4*)&p.ln1b[o];
    pA[2] = *(const float4*)&p.state[0 * NLAYER * NEMBD + o];
    pA[3] = *(const float4*)&p.kktk[o];
    pA[4] = *(const float4*)&p.vvtv[o];
    pA[5] = *(const float4*)&p.rrtr[o];
  };
  auto loadPC = [&](int L) {
    const int o = L * NEMBD + i0;
    pC[0] = *(const float4*)&p.ln2w[o];
    pC[1] = *(const float4*)&p.ln2b[o];
    pC[2] = *(const float4*)&p.state[3 * NLAYER * NEMBD + o];
    pC[3] = *(const float4*)&p.tmk[o];
    pC[4] = *(const float4*)&p.tmr[o];
  };
  auto loadSC = [&](int L) {       // wkv scalars: wave 3, lanes 0-1
    if (wid == 3 && lane < 2) {
      const int ix = L * NEMBD + b * 2 + lane;
      s_tf = p.tf[ix];
      s_sb = p.state[1 * NLAYER * NEMBD + ix];
      s_sc = p.state[2 * NLAYER * NEMBD + ix];
      s_td = p.td[ix];
    }
  };

  // prologue: layer-0 S1/S2 bundles in flight
  loadPA(0); loadKEY(0); loadOV(0); loadSC(0);

  for (int l = 0; l < NLAYER; ++l) {
    const u32 t1 = (u32)(4 * l + 1), t2 = t1 + 1, t3 = t1 + 2, t4 = t1 + 3;
    const bool last = (l == NLAYER - 1);

    // ===== STAGE 1: x -> ln1 -> masks -> k/v/r dots -> wkv (wave 3) =====
    {
      float xa[4];
      if (l == 0) {
        float4 x4 = *(const float4*)&p.x[i0];
        xa[0] = x4.x; xa[1] = x4.y; xa[2] = x4.z; xa[3] = x4.w;
      } else {
        POLL4(QX, i0, (u32)(4 * l), xa);
      }
#pragma unroll
      for (int r = 0; r < 2; ++r) {        // own x elements local for S2
        int gi = b * 2 + r;
        if (t == (gi >> 2)) sm[LXL + r] = xa[gi & 3];
      }
      float s = xa[0] + xa[1] + xa[2] + xa[3];
      float q = xa[0]*xa[0] + xa[1]*xa[1] + xa[2]*xa[2] + xa[3]*xa[3];
      s = wred(s); q = wred(q);
      if (lane == 0) { sm[LLN + wid] = s; sm[LLN + 4 + wid] = q; }
      lbar();                              // B1
      float m  = (sm[LLN+0] + sm[LLN+1] + sm[LLN+2] + sm[LLN+3]) * (1.f / NEMBD);
      float tq = (sm[LLN+4] + sm[LLN+5] + sm[LLN+6] + sm[LLN+7]) * (1.f / NEMBD);
      float rs = rsqrtf(tq - m * m + LN_EPS);
#pragma unroll
      for (int j = 0; j < 4; ++j) {
        int i = i0 + j;
        float xy  = (xa[j] - m) * rs * fcomp(pA[0], j) + fcomp(pA[1], j);
        float sav = fcomp(pA[2], j);
        sm[LMSK + i]        = xy + fcomp(pA[3], j) * sav;
        sm[LMSK + 1024 + i] = xy + fcomp(pA[4], j) * sav;
        sm[LMSK + 2048 + i] = xy + fcomp(pA[5], j) * sav;
        if (t == (b & 255)) p.out[OUT_SA + l * NEMBD + i] = xy;   // statea
      }
      lbar();                              // B2: masks ready
      if (wid < 3) {
        const float* mv = &sm[LMSK + wid * 1024];
#pragma unroll
        for (int idx = 0; idx < 2; ++idx) {
          float a = 0.f;
#pragma unroll
          for (int c = 0; c < 4; ++c)
            a += dot4(wKEY[idx * 4 + c], *(const float4*)&mv[lane * 4 + c * 256]);
          a = wred(a);
          if (lane == 0) sm[LKVR + wid * 2 + idx] = a;
        }
      }
      lbar();                              // B3: kvr ready
      if (wid == 3 && lane < 2) {          // producer-side wkv
        float k = sm[LKVR + lane], v = sm[LKVR + 2 + lane], r = sm[LKVR + 4 + lane];
        float etfk = expf(s_tf + k);
        float er   = expf(r);
        // sc*er + exp(tf+k+r) + sc + etfk == (sc+etfk)*(1+er)
        float wv = (s_sb + etfk * v) / ((s_sc + etfk) * (1.f + er));
        qput(&QW[b * 2 + lane], wv, t1);
        float ek = expf(k), ed = expf(s_td);
        p.out[OUT_SB + l * NEMBD + b * 2 + lane] = s_sb * ed + ek * v;
        p.out[OUT_SC + l * NEMBD + b * 2 + lane] = s_sc * ed + ek;
      }
      stageFF(l); loadPC(l);               // S3 bundle, streams through S2
    }

    // ===== STAGE 2: w -> outputv dots -> sxx =====
    {
      float wv[4];
      POLL4(QW, i0, t1, wv);
#pragma unroll
      for (int j = 0; j < 4; ++j) sm[LACT + i0 + j] = wv[j];
      lbar();                              // B4: w staged
      if (wid < 2) {
        float a = 0.f;
#pragma unroll
        for (int c = 0; c < 4; ++c)
          a += dot4(wOV[c], *(const float4*)&sm[LACT + lane * 4 + c * 256]);
        a = wred(a);
        if (lane == 0) {
          float sxx = sm[LXL + wid] + a;
          qput(&QSXX[b * 2 + wid], sxx, t2);
          sm[LSXL + wid] = sxx;
        }
      }
      loadVF(l);                           // S4 bundle
      lbar();                              // B5: LACT safe to overlay later
    }

    // ===== STAGE 3: sxx -> ln2 -> masks -> ffn dots (LDS slab) =====
    {
      float xa[4];
      POLL4(QSXX, i0, t2, xa);
      float s = xa[0] + xa[1] + xa[2] + xa[3];
      float q = xa[0]*xa[0] + xa[1]*xa[1] + xa[2]*xa[2] + xa[3]*xa[3];
      s = wred(s); q = wred(q);
      if (lane == 0) { sm[LLN + wid] = s; sm[LLN + 4 + wid] = q; }
      lbar();                              // B6
      float m  = (sm[LLN+0] + sm[LLN+1] + sm[LLN+2] + sm[LLN+3]) * (1.f / NEMBD);
      float tq = (sm[LLN+4] + sm[LLN+5] + sm[LLN+6] + sm[LLN+7]) * (1.f / NEMBD);
      float rs = rsqrtf(tq - m * m + LN_EPS);
#pragma unroll
      for (int j = 0; j < 4; ++j) {
        int i = i0 + j;
        float xx  = (xa[j] - m) * rs * fcomp(pC[0], j) + fcomp(pC[1], j);
        float sdv = fcomp(pC[2], j);
        sm[LMSK + i]        = xx + fcomp(pC[3], j) * sdv;   // tmk-mask
        sm[LMSK + 1024 + i] = xx + fcomp(pC[4], j) * sdv;   // tmr-mask
        if (t == (b & 255)) p.out[OUT_SD + l * NEMBD + i] = xx;   // stated
      }
      lbar();                              // B7: masks ready; FF slab landed
                                           // (S2 poll drained older gl2lds)
      {
        const float* mk = &sm[LMSK];
#pragma unroll
        for (int e = 0; e < 2; ++e) {
          const int f = wid * 2 + e;
          const float* slab = &sm[LFF + f * 1024];
          float a = 0.f;
#pragma unroll
          for (int c = 0; c < 4; ++c) {
            int col = lane * 4 + c * 256;
            a += dot4(*(const float4*)&slab[col], *(const float4*)&mk[col]);
          }
          a = wred(a);
          if (lane == 0) {
            float kv = fmaxf(a, 0.f);
            qput(&QKFB[b * 8 + f], kv * kv, t3);
          }
        }
        if (wid < 2) {
          const float* slab = &sm[LFF + (8 + wid) * 1024];
          const float* mr = &sm[LMSK + 1024];
          float a = 0.f;
#pragma unroll
          for (int c = 0; c < 4; ++c) {
            int col = lane * 4 + c * 256;
            a += dot4(*(const float4*)&slab[col], *(const float4*)&mr[col]);
          }
          a = wred(a);
          if (lane == 0) sm[LRFL + wid] = expf(a);
        }
      }
      if (!last) { loadKEY(l + 1); loadPA(l + 1); loadSC(l + 1); }
      lbar();                              // B8: masks/LACT dead -> kf overlay ok
    }

    // ===== STAGE 4: kf -> vffn dots (K-split) -> x' =====
    {
#pragma unroll
      for (int c = 0; c < 4; ++c) {
        float ka[4];
        POLL4(QKFB, c * 1024 + i0, t3, ka);
#pragma unroll
        for (int j = 0; j < 4; ++j) sm[LKF + c * 1024 + i0 + j] = ka[j];
      }
      lbar();                              // B9: kf staged
#pragma unroll
      for (int r = 0; r < 2; ++r) {
        const float* kf = &sm[LKF + wid * 1024];
        float a = 0.f;
#pragma unroll
        for (int c = 0; c < 4; ++c)
          a += dot4(wVF[r * 4 + c], *(const float4*)&kf[lane * 4 + c * 256]);
        a = wred(a);
        if (lane == 0) sm[LPT + r * 4 + wid] = a;
      }
      if (!last) loadOV(l + 1);
      lbar();                              // B10: partials ready
      if (t < 2) {
        float tot = sm[LPT + t * 4 + 0] + sm[LPT + t * 4 + 1]
                  + sm[LPT + t * 4 + 2] + sm[LPT + t * 4 + 3];
        float xn = sm[LSXL + t] + tot / (sm[LRFL + t] + 1.f);
        if (last) p.out[b * 2 + t] = xn;   // final x_out
        else      qput(&QX[b * 2 + t], xn, t4);
      }
    }
  }
}

__global__ void rwkv_init(u64* q) {
  for (int i = 0; i < 28; ++i)
    q[threadIdx.x * 28 + i] = 0ull;
}

extern "C" void kernel_launch(void* const* d_in, const int* in_sizes, int n_in,
                              void* d_out, int out_size, void* d_ws, size_t ws_size,
                              hipStream_t stream) {
  Params p;
  p.x       = (const float*)d_in[0];
  p.state   = (const float*)d_in[1];
  p.ln1w    = (const float*)d_in[2];
  p.ln1b    = (const float*)d_in[3];
  p.ln2w    = (const float*)d_in[4];
  p.ln2b    = (const float*)d_in[5];
  p.td      = (const float*)d_in[6];
  p.tf      = (const float*)d_in[7];
  p.kktk    = (const float*)d_in[8];
  p.vvtv    = (const float*)d_in[9];
  p.rrtr    = (const float*)d_in[10];
  p.key     = (const float*)d_in[11];
  p.outputv = (const float*)d_in[12];
  p.tmk     = (const float*)d_in[13];
  p.tmr     = (const float*)d_in[14];
  p.kffn    = (const float*)d_in[15];
  p.rffn    = (const float*)d_in[16];
  p.vffn    = (const float*)d_in[17];
  p.out     = (float*)d_out;
  p.q       = (u64*)d_ws;            // 7168 u64 = 57344 B

  rwkv_init<<<1, NT, 0, stream>>>(p.q);
  rwkv_persistent<<<NB, NT, 0, stream>>>(p);
}

// Round 18
// 491.409 us; speedup vs baseline: 1.3244x; 1.3244x over previous
//
#include <hip/hip_runtime.h>
#include <math.h>
#include <stddef.h>

#define NLAYER 24
#define NEMBD  1024
#define NFFN   4096
#define NB     256
#define NT     256
#define LN_EPS 1e-5f

#define OUT_SA (NEMBD)
#define OUT_SB (NEMBD + NLAYER*NEMBD)
#define OUT_SC (NEMBD + 2*NLAYER*NEMBD)
#define OUT_SD (NEMBD + 3*NLAYER*NEMBD)

typedef unsigned long long u64;
typedef unsigned u32;

// tagged-word queues (u64: tag<<32 | float bits), data IS the sync signal
#define QX_OFF    0        // 1024: x' per layer
#define QW_OFF    1024     // 1024: w vector (producer-side wkv)
#define QSXX_OFF  2048     // 1024: sxx
#define QKFB_OFF  3072     // 4096: kf
#define QTOTAL    7168

// LDS float offsets
#define LMSK  0            // 3072: ln masks / staged w vector
#define LACT  3072         // 4096: staged kf
#define LFF   7168         // 4 x 5120: per-wave FFN weight slabs (80 KB)
#define LLN   27648        // 8: LN partials
#define LXL   27656        // 4: x[b*4+r]   (s1 -> s2)
#define LSXL  27660        // 4: sxx[b*4+r] (s2 -> s4)
#define LRFL  27664        // 4: rf[b*4+r]  (s3 -> s4)
#define LPT   27668        // 16: s4 K-split partials [r*4+wave]
#define SMTOT 27684        // 110736 B

struct Params {
  const float *x, *state, *ln1w, *ln1b, *ln2w, *ln2b, *td, *tf, *kktk, *vvtv, *rrtr;
  const float *key, *outputv, *tmk, *tmr, *kffn, *rffn, *vffn;
  float *out;
  u64 *q;
};

__device__ __forceinline__ float wred(float v) {
#pragma unroll
  for (int o = 32; o > 0; o >>= 1) v += __shfl_xor(v, o, 64);
  return v;
}
__device__ __forceinline__ float dot4(float4 a, float4 b) {
  return a.x*b.x + a.y*b.y + a.z*b.z + a.w*b.w;
}
__device__ __forceinline__ float fcomp(float4 v, int j) {   // literal j only
  return j == 0 ? v.x : (j == 1 ? v.y : (j == 2 ? v.z : v.w));
}
__device__ __forceinline__ u64 qload(const u64* a) {
  return __hip_atomic_load(a, __ATOMIC_RELAXED, __HIP_MEMORY_SCOPE_AGENT);
}
__device__ __forceinline__ void qput(u64* a, float v, u32 tag) {
  u64 w = ((u64)tag << 32) | (u64)__float_as_uint(v);
  __hip_atomic_store(a, w, __ATOMIC_RELAXED, __HIP_MEMORY_SCOPE_AGENT);
}
__device__ __forceinline__ u32   qtag(u64 w) { return (u32)(w >> 32); }
__device__ __forceinline__ float qval(u64 w) { return __uint_as_float((u32)w); }

// async global->LDS, 16B/lane: dest = wave-uniform base + lane*16
__device__ __forceinline__ void stage16(const float* g, float* l) {
  __builtin_amdgcn_global_load_lds(
      (const __attribute__((address_space(1))) unsigned int*)g,
      (__attribute__((address_space(3))) unsigned int*)l, 16, 0, 0);
}

// intra-block barrier: LDS ordering only; weight vmem stays in flight
__device__ __forceinline__ void lbar() {
  asm volatile("s_waitcnt lgkmcnt(0)" ::: "memory");
  __builtin_amdgcn_s_barrier();
  asm volatile("" ::: "memory");
}

// Sleep-before-poll: each s_sleep(16) ~ 1024 cy ~ 0.43 us. The sleep gives
// the in-flight weight bundle (issued at prev stage end) an undisturbed
// landing window; the poll's first-use drain then retires only the residue.
#define POLL4S(QB, IDX, TG, OUTA, SREP)                                       \
  do {                                                                        \
    for (int z_ = 0; z_ < (SREP); ++z_) __builtin_amdgcn_s_sleep(16);         \
    u64 a0_, a1_, a2_, a3_; long cc_ = 0;                                     \
    for (;;) {                                                                \
      a0_ = qload((QB) + (IDX) + 0); a1_ = qload((QB) + (IDX) + 1);           \
      a2_ = qload((QB) + (IDX) + 2); a3_ = qload((QB) + (IDX) + 3);           \
      if (qtag(a0_) >= (TG) && qtag(a1_) >= (TG) &&                           \
          qtag(a2_) >= (TG) && qtag(a3_) >= (TG)) break;                      \
      __builtin_amdgcn_s_sleep(1);                                            \
      if (++cc_ > (1L << 20)) break;  /* safety: wrong beats hang */          \
    }                                                                         \
    OUTA[0] = qval(a0_); OUTA[1] = qval(a1_);                                 \
    OUTA[2] = qval(a2_); OUTA[3] = qval(a3_);                                 \
  } while (0)

__global__ void __launch_bounds__(NT, 1)
rwkv_persistent(Params p) {
  const int b    = blockIdx.x;
  const int t    = threadIdx.x;
  const int wid  = t >> 6;
  const int lane = t & 63;
  const int i0   = t * 4;
  const int myi  = b * 4 + wid;     // this wave's owned vector index

  __shared__ float sm[SMTOT];

  u64* QX   = p.q + QX_OFF;
  u64* QW   = p.q + QW_OFF;
  u64* QSXX = p.q + QSXX_OFF;
  u64* QKFB = p.q + QKFB_OFF;

  float4 wKEY[12];   // s1: k,v,r rows for index myi
  float4 wOV[4];     // s2: outputv row myi
  float4 wVF[16];    // s4: vffn 4 rows x this wave's 4 K-chunks
  float4 pA[6];      // s1 params
  float4 pC[5];      // s3 params
  float s_tf, s_sb, s_sc, s_td;   // lane0 wkv scalars for index myi

  auto loadKEY = [&](int L) {
#pragma unroll
    for (int mth = 0; mth < 3; ++mth) {
      const float* W = p.key + ((size_t)L * 3 + mth) * NEMBD * NEMBD
                     + (size_t)myi * NEMBD + lane * 4;
#pragma unroll
      for (int c = 0; c < 4; ++c)
        wKEY[mth * 4 + c] = *(const float4*)&W[c * 256];
    }
  };
  auto loadOV = [&](int L) {
    const float* W = p.outputv + ((size_t)L * NEMBD + myi) * NEMBD + lane * 4;
#pragma unroll
    for (int c = 0; c < 4; ++c)
      wOV[c] = *(const float4*)&W[c * 256];
  };
  auto loadVF = [&](int L) {
#pragma unroll
    for (int r = 0; r < 4; ++r) {
      const float* W = p.vffn + ((size_t)L * NEMBD + b * 4 + r) * NFFN + lane * 4;
#pragma unroll
      for (int c = 0; c < 4; ++c)
        wVF[r * 4 + c] = *(const float4*)&W[(wid * 4 + c) * 256];
    }
  };
  auto stageFF = [&](int L) {       // 4 kffn rows + 1 rffn row -> own LDS slab
    float* slab = &sm[LFF + wid * 5120];
#pragma unroll
    for (int q = 0; q < 4; ++q) {
      const float* W = p.kffn + ((size_t)L * NFFN + b * 16 + wid * 4 + q) * NEMBD;
#pragma unroll
      for (int c = 0; c < 4; ++c)
        stage16(W + c * 256 + lane * 4, slab + q * 1024 + c * 256);
    }
    const float* Wr = p.rffn + ((size_t)L * NEMBD + myi) * NEMBD;
#pragma unroll
    for (int c = 0; c < 4; ++c)
      stage16(Wr + c * 256 + lane * 4, slab + 4096 + c * 256);
  };
  auto loadPA = [&](int L) {
    const int o = L * NEMBD + i0;
    pA[0] = *(const float4*)&p.ln1w[o];
    pA[1] = *(const float4*)&p.ln1b[o];
    pA[2] = *(const float4*)&p.state[0 * NLAYER * NEMBD + o];
    pA[3] = *(const float4*)&p.kktk[o];
    pA[4] = *(const float4*)&p.vvtv[o];
    pA[5] = *(const float4*)&p.rrtr[o];
    if (lane == 0) {
      const int ix = L * NEMBD + myi;
      s_tf = p.tf[ix];
      s_sb = p.state[1 * NLAYER * NEMBD + ix];
      s_sc = p.state[2 * NLAYER * NEMBD + ix];
      s_td = p.td[ix];
    }
  };
  auto loadPC = [&](int L) {
    const int o = L * NEMBD + i0;
    pC[0] = *(const float4*)&p.ln2w[o];
    pC[1] = *(const float4*)&p.ln2b[o];
    pC[2] = *(const float4*)&p.state[3 * NLAYER * NEMBD + o];
    pC[3] = *(const float4*)&p.tmk[o];
    pC[4] = *(const float4*)&p.tmr[o];
  };

  // prologue: layer-0 s1/s2 bundles + params in flight
  loadPA(0); loadKEY(0); loadOV(0);

  for (int l = 0; l < NLAYER; ++l) {
    const u32 t1 = (u32)(4 * l + 1), t2 = t1 + 1, t3 = t1 + 2, t4 = t1 + 3;

    // ===== STAGE 1: x -> ln1 -> masks -> k/v/r dots -> wkv (producer) =====
    {
      float xa[4];
      if (l == 0) {
        float4 x4 = *(const float4*)&p.x[i0];
        xa[0] = x4.x; xa[1] = x4.y; xa[2] = x4.z; xa[3] = x4.w;
      } else {
        POLL4S(QX, i0, (u32)(4 * l), xa, 1);    // OV bundle ~16KB: short nap
      }
      if (t == b) {                       // own x slice local for stage 2
#pragma unroll
        for (int j = 0; j < 4; ++j) sm[LXL + j] = xa[j];
      }
      float s = xa[0] + xa[1] + xa[2] + xa[3];
      float q = xa[0]*xa[0] + xa[1]*xa[1] + xa[2]*xa[2] + xa[3]*xa[3];
      s = wred(s); q = wred(q);
      if (lane == 0) { sm[LLN + wid] = s; sm[LLN + 4 + wid] = q; }
      lbar();
      float m  = (sm[LLN+0] + sm[LLN+1] + sm[LLN+2] + sm[LLN+3]) * (1.f / NEMBD);
      float tq = (sm[LLN+4] + sm[LLN+5] + sm[LLN+6] + sm[LLN+7]) * (1.f / NEMBD);
      float rs = rsqrtf(tq - m * m + LN_EPS);
#pragma unroll
      for (int j = 0; j < 4; ++j) {
        int i = i0 + j;
        float xy  = (xa[j] - m) * rs * fcomp(pA[0], j) + fcomp(pA[1], j);
        float sav = fcomp(pA[2], j);
        sm[LMSK + i]        = xy + fcomp(pA[3], j) * sav;
        sm[LMSK + 1024 + i] = xy + fcomp(pA[4], j) * sav;
        sm[LMSK + 2048 + i] = xy + fcomp(pA[5], j) * sav;
        if (t == b) p.out[OUT_SA + l * NEMBD + i] = xy;   // statea: own slice
      }
      lbar();                                             // masks ready
      float a0 = 0.f, a1 = 0.f, a2 = 0.f;
#pragma unroll
      for (int c = 0; c < 4; ++c) {
        int col = lane * 4 + c * 256;
        a0 += dot4(wKEY[c],     *(const float4*)&sm[LMSK + col]);
        a1 += dot4(wKEY[4 + c], *(const float4*)&sm[LMSK + 1024 + col]);
        a2 += dot4(wKEY[8 + c], *(const float4*)&sm[LMSK + 2048 + col]);
      }
      a0 = wred(a0); a1 = wred(a1); a2 = wred(a2);
      if (lane == 0) {                    // producer-side wkv combine
        float etfk = expf(s_tf + a0);
        float er   = expf(a2);
        // sc*er + exp(tf+k+r) + sc + etfk == (sc+etfk)*(1+er)
        float wv = (s_sb + etfk * a1) / ((s_sc + etfk) * (1.f + er));
        qput(&QW[myi], wv, t1);
        float ek = expf(a0), ed = expf(s_td);
        p.out[OUT_SB + l * NEMBD + myi] = s_sb * ed + ek * a1;   // distributed
        p.out[OUT_SC + l * NEMBD + myi] = s_sc * ed + ek;
      }
      stageFF(l); loadPC(l);              // next bundles, in flight
      lbar();                             // stage end (LMSK reuse barrier)
    }

    // ===== STAGE 2: w -> outputv dot -> sxx =====
    {
      float wv[4];
      POLL4S(QW, i0, t1, wv, 5);          // FF+pC ~100KB: ~2.1us nap
#pragma unroll
      for (int j = 0; j < 4; ++j) sm[LMSK + i0 + j] = wv[j];
      lbar();                             // w vector staged
      float acc = 0.f;
#pragma unroll
      for (int c = 0; c < 4; ++c)
        acc += dot4(wOV[c], *(const float4*)&sm[LMSK + lane * 4 + c * 256]);
      acc = wred(acc);
      if (lane == 0) {
        float sxx = sm[LXL + wid] + acc;
        qput(&QSXX[myi], sxx, t2);
        sm[LSXL + wid] = sxx;             // local for stage 4
      }
      loadVF(l);                          // s4 bundle, in flight
      lbar();                             // stage end
    }

    // ===== STAGE 3: sxx -> ln2 -> masks -> ffn dots (LDS weights) =====
    {
      float xa[4];
      POLL4S(QSXX, i0, t2, xa, 4);        // VF ~64KB: ~1.7us nap
      float s = xa[0] + xa[1] + xa[2] + xa[3];
      float q = xa[0]*xa[0] + xa[1]*xa[1] + xa[2]*xa[2] + xa[3]*xa[3];
      s = wred(s); q = wred(q);
      if (lane == 0) { sm[LLN + wid] = s; sm[LLN + 4 + wid] = q; }
      lbar();
      float m  = (sm[LLN+0] + sm[LLN+1] + sm[LLN+2] + sm[LLN+3]) * (1.f / NEMBD);
      float tq = (sm[LLN+4] + sm[LLN+5] + sm[LLN+6] + sm[LLN+7]) * (1.f / NEMBD);
      float rs = rsqrtf(tq - m * m + LN_EPS);
#pragma unroll
      for (int j = 0; j < 4; ++j) {
        int i = i0 + j;
        float xx  = (xa[j] - m) * rs * fcomp(pC[0], j) + fcomp(pC[1], j);
        float sdv = fcomp(pC[2], j);
        sm[LMSK + i]        = xx + fcomp(pC[3], j) * sdv;
        sm[LMSK + 1024 + i] = xx + fcomp(pC[4], j) * sdv;
        if (t == b) p.out[OUT_SD + l * NEMBD + i] = xx;   // stated: own slice
      }
      lbar();                             // masks ready; FF slab landed
      const float* slab = &sm[LFF + wid * 5120];
#pragma unroll
      for (int q2 = 0; q2 < 4; ++q2) {
        float a = 0.f;
#pragma unroll
        for (int c = 0; c < 4; ++c) {
          int col = lane * 4 + c * 256;
          a += dot4(*(const float4*)&slab[q2 * 1024 + col],
                    *(const float4*)&sm[LMSK + col]);
        }
        a = wred(a);
        if (lane == 0) {
          float kv = fmaxf(a, 0.f);
          qput(&QKFB[b * 16 + wid * 4 + q2], kv * kv, t3);
        }
      }
      {
        float a = 0.f;
#pragma unroll
        for (int c = 0; c < 4; ++c) {
          int col = lane * 4 + c * 256;
          a += dot4(*(const float4*)&slab[4096 + col],
                    *(const float4*)&sm[LMSK + 1024 + col]);
        }
        a = wred(a);
        if (lane == 0) sm[LRFL + wid] = expf(a);   // block-local only
      }
      if (l + 1 < NLAYER) { loadKEY(l + 1); loadPA(l + 1); }
      lbar();                             // stage end
    }

    // ===== STAGE 4: kf -> vffn dot (K-split) -> x' =====
    {
      {
        float ka[4];
        POLL4S(QKFB, 0 * 1024 + i0, t3, ka, 4);   // KEY'+pA' ~72KB: ~1.7us
#pragma unroll
        for (int j = 0; j < 4; ++j) sm[LACT + 0 * 1024 + i0 + j] = ka[j];
      }
#pragma unroll
      for (int c = 1; c < 4; ++c) {
        float ka[4];
        POLL4S(QKFB, c * 1024 + i0, t3, ka, 0);
#pragma unroll
        for (int j = 0; j < 4; ++j) sm[LACT + c * 1024 + i0 + j] = ka[j];
      }
      lbar();                             // kf staged
#pragma unroll
      for (int r = 0; r < 4; ++r) {
        float a = 0.f;
#pragma unroll
        for (int c = 0; c < 4; ++c)
          a += dot4(wVF[r * 4 + c],
                    *(const float4*)&sm[LACT + lane * 4 + (wid * 4 + c) * 256]);
        a = wred(a);
        if (lane == 0) sm[LPT + r * 4 + wid] = a;
      }
      if (l + 1 < NLAYER) loadOV(l + 1);
      lbar();                             // partials ready
      if (t < 4) {
        float tot = sm[LPT + t * 4 + 0] + sm[LPT + t * 4 + 1]
                  + sm[LPT + t * 4 + 2] + sm[LPT + t * 4 + 3];
        float xn = sm[LSXL + t] + tot / (sm[LRFL + t] + 1.f);
        if (l == NLAYER - 1) p.out[b * 4 + t] = xn;   // final x_out
        else                 qput(&QX[b * 4 + t], xn, t4);
      }
    }
  }
}

__global__ void rwkv_init(u64* q) {
  for (int i = 0; i < 28; ++i)
    q[threadIdx.x * 28 + i] = 0ull;
}

extern "C" void kernel_launch(void* const* d_in, const int* in_sizes, int n_in,
                              void* d_out, int out_size, void* d_ws, size_t ws_size,
                              hipStream_t stream) {
  Params p;
  p.x       = (const float*)d_in[0];
  p.state   = (const float*)d_in[1];
  p.ln1w    = (const float*)d_in[2];
  p.ln1b    = (const float*)d_in[3];
  p.ln2w    = (const float*)d_in[4];
  p.ln2b    = (const float*)d_in[5];
  p.td      = (const float*)d_in[6];
  p.tf      = (const float*)d_in[7];
  p.kktk    = (const float*)d_in[8];
  p.vvtv    = (const float*)d_in[9];
  p.rrtr    = (const float*)d_in[10];
  p.key     = (const float*)d_in[11];
  p.outputv = (const float*)d_in[12];
  p.tmk     = (const float*)d_in[13];
  p.tmr     = (const float*)d_in[14];
  p.kffn    = (const float*)d_in[15];
  p.rffn    = (const float*)d_in[16];
  p.vffn    = (const float*)d_in[17];
  p.out     = (float*)d_out;
  p.q       = (u64*)d_ws;            // 7168 u64 = 57344 B

  rwkv_init<<<1, NB, 0, stream>>>(p.q);
  rwkv_persistent<<<NB, NT, 0, stream>>>(p);
}